// Round 1
// baseline (652.832 us; speedup 1.0000x reference)
//
#include <hip/hip_runtime.h>

#define NN 50000   // nodes
#define NE 800000  // edges
#define DD 256     // feature dim
#define NX 8       // experts

typedef short s8v __attribute__((ext_vector_type(8)));   // 8 x bf16 (as i16)
typedef float f4v __attribute__((ext_vector_type(4)));   // MFMA accumulator

static __device__ __forceinline__ unsigned short f2bf(float f) {
  unsigned u = __builtin_bit_cast(unsigned, f);
  u = (u + 0x7fffu + ((u >> 16) & 1u)) >> 16;  // RNE
  return (unsigned short)u;
}

// ---------------- CSR build ----------------
__global__ void k_deg(const int* __restrict__ ei, int* __restrict__ deg) {
  int e = blockIdx.x * 256 + threadIdx.x;
  if (e < NE) atomicAdd(&deg[ei[NE + e]], 1);  // dst row
}

__global__ void k_scan(const int* __restrict__ deg, int* __restrict__ rowptr,
                       int* __restrict__ cursor) {
  __shared__ int buf[2][1024];
  __shared__ int carry_s;
  int t = threadIdx.x;
  if (t == 0) carry_s = 0;
  __syncthreads();
  for (int base = 0; base < NN; base += 1024) {
    int v = (base + t < NN) ? deg[base + t] : 0;
    int cur = 0;
    buf[0][t] = v;
    __syncthreads();
    for (int off = 1; off < 1024; off <<= 1) {
      int s = buf[cur][t];
      if (t >= off) s += buf[cur][t - off];
      buf[cur ^ 1][t] = s;
      cur ^= 1;
      __syncthreads();
    }
    int incl = buf[cur][t];
    int carry = carry_s;
    if (base + t < NN) {
      int excl = carry + incl - v;
      rowptr[base + t] = excl;
      cursor[base + t] = excl;
    }
    __syncthreads();
    if (t == 1023) carry_s = carry + buf[cur][1023];
    __syncthreads();
  }
  if (t == 0) rowptr[NN] = carry_s;  // == NE
}

__global__ void k_scatter(const int* __restrict__ ei, int* __restrict__ cursor,
                          int* __restrict__ csr) {
  int e = blockIdx.x * 256 + threadIdx.x;
  if (e < NE) {
    int s = ei[e];        // src
    int d = ei[NE + e];   // dst
    int p = atomicAdd(&cursor[d], 1);
    csr[p] = s;
  }
}

// ---------------- aggregation: one wave per node ----------------
__global__ __launch_bounds__(256) void k_agg(const float* __restrict__ x,
                                             const int* __restrict__ rowptr,
                                             const int* __restrict__ csr,
                                             float* __restrict__ agg) {
  int wave = threadIdx.x >> 6, lane = threadIdx.x & 63;
  int n = blockIdx.x * 4 + wave;  // 12500 blocks * 4 waves == 50000
  int i0 = rowptr[n], i1 = rowptr[n + 1];
  float4 acc = make_float4(0.f, 0.f, 0.f, 0.f);
  const float4* xp = (const float4*)x;
  for (int i = i0; i < i1; i++) {
    int s = csr[i];
    float4 v = xp[(size_t)s * 64 + lane];
    acc.x += v.x; acc.y += v.y; acc.z += v.z; acc.w += v.w;
  }
  ((float4*)agg)[(size_t)n * 64 + lane] = acc;
}

// ---------------- W_exp -> bf16 transpose Wt[e][o][d] ----------------
__global__ void k_wt(const float* __restrict__ We, unsigned short* __restrict__ Wt) {
  int i = blockIdx.x * 256 + threadIdx.x;  // 8*256*256 == 524288 exact
  int e = i >> 16, rem = i & 0xffff, o = rem >> 8, d = rem & 255;
  Wt[i] = f2bf(We[(e << 16) + (d << 8) + o]);
}

// ---------------- gate: logits, top-3 (stable), softmax, aux stats ----------------
__global__ __launch_bounds__(256) void k_gate(const float* __restrict__ agg,
                                              const float* __restrict__ Wg,
                                              const float* __restrict__ bg,
                                              unsigned short* __restrict__ aggb,
                                              float* __restrict__ gates,
                                              float* __restrict__ imp,
                                              int* __restrict__ loadc) {
  __shared__ float s_imp[NX];
  __shared__ int s_load[NX];
  int t = threadIdx.x;
  if (t < NX) { s_imp[t] = 0.f; s_load[t] = 0; }
  __syncthreads();
  int wave = t >> 6, lane = t & 63;
  for (int n = blockIdx.x * 4 + wave; n < NN; n += gridDim.x * 4) {
    float4 a = ((const float4*)agg)[(size_t)n * 64 + lane];
    ushort4 ab;
    ab.x = f2bf(a.x); ab.y = f2bf(a.y); ab.z = f2bf(a.z); ab.w = f2bf(a.w);
    ((ushort4*)aggb)[(size_t)n * 64 + lane] = ab;

    float p[NX];
#pragma unroll
    for (int e = 0; e < NX; e++) p[e] = 0.f;
    const float* wr = Wg + lane * 4 * NX;
    float av[4] = {a.x, a.y, a.z, a.w};
#pragma unroll
    for (int j = 0; j < 4; j++)
#pragma unroll
      for (int e = 0; e < NX; e++) p[e] = fmaf(av[j], wr[j * NX + e], p[e]);
#pragma unroll
    for (int off = 32; off > 0; off >>= 1)
#pragma unroll
      for (int e = 0; e < NX; e++) p[e] += __shfl_xor(p[e], off, 64);

    float lg[NX];
#pragma unroll
    for (int e = 0; e < NX; e++) lg[e] = fmaxf(p[e] + bg[e], 0.f);

    // top-3 with lowest-index tie-break (matches stable lax.top_k)
    int ti0 = 0, ti1 = 0, ti2 = 0;
    float tv0 = -1.f, tv1 = -1.f, tv2 = -1.f;
#pragma unroll
    for (int e = 0; e < NX; e++) if (lg[e] > tv0) { tv0 = lg[e]; ti0 = e; }
#pragma unroll
    for (int e = 0; e < NX; e++) if (e != ti0 && lg[e] > tv1) { tv1 = lg[e]; ti1 = e; }
#pragma unroll
    for (int e = 0; e < NX; e++) if (e != ti0 && e != ti1 && lg[e] > tv2) { tv2 = lg[e]; ti2 = e; }

    float e0 = 1.f, e1 = expf(tv1 - tv0), e2 = expf(tv2 - tv0);
    float inv = 1.f / (e0 + e1 + e2);
    float g0 = e0 * inv, g1 = e1 * inv, g2 = e2 * inv;

    if (lane == 0) {
      float go[NX];
#pragma unroll
      for (int e = 0; e < NX; e++)
        go[e] = (e == ti0) ? g0 : ((e == ti1) ? g1 : ((e == ti2) ? g2 : 0.f));
      float4* gp = (float4*)(gates + (size_t)n * NX);
      gp[0] = make_float4(go[0], go[1], go[2], go[3]);
      gp[1] = make_float4(go[4], go[5], go[6], go[7]);
      atomicAdd(&s_imp[ti0], g0); atomicAdd(&s_imp[ti1], g1); atomicAdd(&s_imp[ti2], g2);
      atomicAdd(&s_load[ti0], 1); atomicAdd(&s_load[ti1], 1); atomicAdd(&s_load[ti2], 1);
    }
  }
  __syncthreads();
  if (t < NX) { atomicAdd(&imp[t], s_imp[t]); atomicAdd(&loadc[t], s_load[t]); }
}

// ---------------- aux loss ----------------
__global__ void k_loss(const float* __restrict__ imp, const int* __restrict__ loadc,
                       float* __restrict__ out) {
  if (threadIdx.x == 0 && blockIdx.x == 0) {
    double mi = 0, ml = 0;
    for (int e = 0; e < NX; e++) { mi += imp[e]; ml += (double)loadc[e]; }
    mi *= 0.125; ml *= 0.125;
    double vi = 0, vl = 0;
    for (int e = 0; e < NX; e++) {
      double di = imp[e] - mi, dl = (double)loadc[e] - ml;
      vi += di * di; vl += dl * dl;
    }
    vi /= 7.0; vl /= 7.0;  // ddof=1
    double cv = vi / (mi * mi + 1e-10) + vl / (ml * ml + 1e-10);
    out[0] = (float)(0.01 * cv);
  }
}

// ---------------- experts: dense 8-expert bf16 MFMA, gate+bias folded ----------------
__global__ __launch_bounds__(256) void k_y(const unsigned short* __restrict__ aggb,
                                           const unsigned short* __restrict__ Wt,
                                           const float* __restrict__ gates,
                                           const float* __restrict__ be,
                                           float* __restrict__ y) {
  __shared__ float ldsg[32][NX];
  int t = threadIdx.x;
  int r0 = blockIdx.x * 32;
  {
    int row = t >> 3, e = t & 7;
    int gr = r0 + row;
    ldsg[row][e] = (gr < NN) ? gates[(size_t)gr * NX + e] : 0.f;
  }
  __syncthreads();
  int wave = t >> 6, lane = t & 63;
  int l15 = lane & 15, lgp = lane >> 4;

  // A fragments: 2 row-frags x 8 K-steps, kept across all experts
  s8v afr[2][8];
#pragma unroll
  for (int rf = 0; rf < 2; rf++) {
    int row = r0 + rf * 16 + l15;
    if (row > NN - 1) row = NN - 1;  // clamp; gate==0 kills the contribution
    const unsigned short* ap = aggb + (size_t)row * DD + lgp * 8;
#pragma unroll
    for (int ks = 0; ks < 8; ks++) afr[rf][ks] = *(const s8v*)(ap + ks * 32);
  }

  f4v yac[2][4];
#pragma unroll
  for (int rf = 0; rf < 2; rf++)
#pragma unroll
    for (int cf = 0; cf < 4; cf++) yac[rf][cf] = (f4v)0.0f;

  for (int e = 0; e < NX; e++) {
    f4v ac[2][4];
#pragma unroll
    for (int rf = 0; rf < 2; rf++)
#pragma unroll
      for (int cf = 0; cf < 4; cf++) ac[rf][cf] = (f4v)0.0f;

#pragma unroll
    for (int ks = 0; ks < 8; ks++) {
#pragma unroll
      for (int cf = 0; cf < 4; cf++) {
        int col = wave * 64 + cf * 16 + l15;
        s8v b = *(const s8v*)(Wt + (((e << 8) + col) << 8) + ks * 32 + lgp * 8);
        ac[0][cf] = __builtin_amdgcn_mfma_f32_16x16x32_bf16(afr[0][ks], b, ac[0][cf], 0, 0, 0);
        ac[1][cf] = __builtin_amdgcn_mfma_f32_16x16x32_bf16(afr[1][ks], b, ac[1][cf], 0, 0, 0);
      }
    }
    float bec[4];
#pragma unroll
    for (int cf = 0; cf < 4; cf++) bec[cf] = be[(e << 8) + wave * 64 + cf * 16 + l15];
#pragma unroll
    for (int rf = 0; rf < 2; rf++)
#pragma unroll
      for (int r = 0; r < 4; r++) {
        float g = ldsg[rf * 16 + lgp * 4 + r][e];
#pragma unroll
        for (int cf = 0; cf < 4; cf++)
          yac[rf][cf][r] += g * (ac[rf][cf][r] + bec[cf]);
      }
  }
#pragma unroll
  for (int rf = 0; rf < 2; rf++)
#pragma unroll
    for (int r = 0; r < 4; r++) {
      int row = r0 + rf * 16 + lgp * 4 + r;
      if (row < NN) {
#pragma unroll
        for (int cf = 0; cf < 4; cf++)
          y[(size_t)row * DD + wave * 64 + cf * 16 + l15] = yac[rf][cf][r];
      }
    }
}

extern "C" void kernel_launch(void* const* d_in, const int* in_sizes, int n_in,
                              void* d_out, int out_size, void* d_ws, size_t ws_size,
                              hipStream_t stream) {
  const float* x  = (const float*)d_in[0];
  const int*   ei = (const int*)d_in[1];
  const float* Wg = (const float*)d_in[2];
  const float* bg = (const float*)d_in[3];
  const float* We = (const float*)d_in[4];
  const float* be = (const float*)d_in[5];
  float* y = (float*)d_out;  // [NN*DD] then loss scalar at [NN*DD]

  char* w = (char*)d_ws;
  auto alloc = [&](size_t bytes) {
    char* p = w;
    w += (bytes + 255) & ~(size_t)255;
    return p;
  };
  float*          agg    = (float*)alloc((size_t)NN * DD * 4);
  unsigned short* aggb   = (unsigned short*)alloc((size_t)NN * DD * 2);
  unsigned short* Wt     = (unsigned short*)alloc((size_t)NX * DD * DD * 2);
  float*          gates  = (float*)alloc((size_t)NN * NX * 4);
  int*            rowptr = (int*)alloc((size_t)(NN + 1) * 4);
  int*            cursor = (int*)alloc((size_t)NN * 4);
  int*            csr    = (int*)alloc((size_t)NE * 4);
  int*            deg    = (int*)alloc((size_t)NN * 4 + 64);  // deg | imp | loadc
  float*          imp    = (float*)(deg + NN);
  int*            loadc  = deg + NN + 8;

  hipMemsetAsync(deg, 0, (size_t)NN * 4 + 64, stream);
  k_deg<<<(NE + 255) / 256, 256, 0, stream>>>(ei, deg);
  k_scan<<<1, 1024, 0, stream>>>(deg, rowptr, cursor);
  k_scatter<<<(NE + 255) / 256, 256, 0, stream>>>(ei, cursor, csr);
  k_wt<<<(NX * DD * DD) / 256, 256, 0, stream>>>(We, Wt);
  k_agg<<<NN / 4, 256, 0, stream>>>(x, rowptr, csr, agg);
  k_gate<<<512, 256, 0, stream>>>(agg, Wg, bg, aggb, gates, imp, loadc);
  k_loss<<<1, 64, 0, stream>>>(imp, loadc, y + (size_t)NN * DD);
  k_y<<<(NN + 31) / 32, 256, 0, stream>>>(aggb, Wt, gates, be, y);
}

// Round 2
// 616.155 us; speedup vs baseline: 1.0595x; 1.0595x over previous
//
#include <hip/hip_runtime.h>

#define NN 50000   // nodes
#define NE 800000  // edges
#define DD 256     // feature dim
#define NX 8       // experts
#define BM 128     // k_y rows per block
#define BN 128     // k_y cols per block

typedef short s8v __attribute__((ext_vector_type(8)));   // 8 x bf16 (as i16)
typedef float f4v __attribute__((ext_vector_type(4)));   // MFMA accumulator

#define AS1 __attribute__((address_space(1)))
#define AS3 __attribute__((address_space(3)))

static __device__ __forceinline__ unsigned short f2bf(float f) {
  unsigned u = __builtin_bit_cast(unsigned, f);
  u = (u + 0x7fffu + ((u >> 16) & 1u)) >> 16;  // RNE
  return (unsigned short)u;
}

// ---------------- CSR build ----------------
__global__ void k_deg(const int* __restrict__ ei, int* __restrict__ deg) {
  int e = blockIdx.x * 256 + threadIdx.x;
  if (e < NE) atomicAdd(&deg[ei[NE + e]], 1);  // dst row
}

// 49 blocks x 1024: per-block exclusive scan -> rowptr, block totals -> bsum
__global__ void k_scan1(const int* __restrict__ deg, int* __restrict__ rowptr,
                        int* __restrict__ bsum) {
  __shared__ int buf[2][1024];
  int t = threadIdx.x, base = blockIdx.x * 1024;
  int v = (base + t < NN) ? deg[base + t] : 0;
  buf[0][t] = v;
  int cur = 0;
  __syncthreads();
  for (int off = 1; off < 1024; off <<= 1) {
    int s = buf[cur][t];
    if (t >= off) s += buf[cur][t - off];
    buf[cur ^ 1][t] = s;
    cur ^= 1;
    __syncthreads();
  }
  if (base + t < NN) rowptr[base + t] = buf[cur][t] - v;  // within-block exclusive
  if (t == 1023) bsum[blockIdx.x] = buf[cur][1023];
}

// 1 block: scan the 49 block sums
__global__ void k_scan2(const int* __restrict__ bsum, int* __restrict__ boff,
                        int* __restrict__ rowptr) {
  int l = threadIdx.x;
  int v = (l < 49) ? bsum[l] : 0;
  int s = v;
  for (int off = 1; off < 64; off <<= 1) {
    int o = __shfl_up(s, off, 64);
    if (l >= off) s += o;
  }
  if (l < 49) boff[l] = s - v;
  if (l == 0) rowptr[NN] = NE;
}

// add block offsets; produce cursor copy
__global__ void k_scan3(int* __restrict__ rowptr, const int* __restrict__ boff,
                        int* __restrict__ cursor) {
  int i = blockIdx.x * 1024 + threadIdx.x;
  if (i < NN) {
    int r = rowptr[i] + boff[blockIdx.x];
    rowptr[i] = r;
    cursor[i] = r;
  }
}

__global__ void k_scatter(const int* __restrict__ ei, int* __restrict__ cursor,
                          int* __restrict__ csr) {
  int e = blockIdx.x * 256 + threadIdx.x;
  if (e < NE) {
    int s = ei[e];        // src
    int d = ei[NE + e];   // dst
    int p = atomicAdd(&cursor[d], 1);
    csr[p] = s;
  }
}

// ---------------- W_exp -> bf16 transpose Wt[e][o][d] ----------------
__global__ void k_wt(const float* __restrict__ We, unsigned short* __restrict__ Wt) {
  int i = blockIdx.x * 256 + threadIdx.x;  // 8*256*256 == 524288 exact
  int e = i >> 16, rem = i & 0xffff, o = rem >> 8, d = rem & 255;
  Wt[i] = f2bf(We[(e << 16) + (d << 8) + o]);
}

// ---------------- fused aggregation + gate ----------------
__global__ __launch_bounds__(256) void k_agggate(
    const float* __restrict__ x, const int* __restrict__ rowptr,
    const int* __restrict__ csr, const float* __restrict__ Wg,
    const float* __restrict__ bg, unsigned short* __restrict__ aggb,
    float* __restrict__ gates, float* __restrict__ imp, int* __restrict__ loadc) {
  __shared__ float s_imp[NX];
  __shared__ int s_load[NX];
  int t = threadIdx.x;
  if (t < NX) { s_imp[t] = 0.f; s_load[t] = 0; }
  __syncthreads();
  int wv = t >> 6, lane = t & 63;
  int n = blockIdx.x * 4 + wv;  // 12500 blocks * 4 waves == 50000
  int i0 = rowptr[n], i1 = rowptr[n + 1];
  const float4* xp = (const float4*)x;
  float4 a = make_float4(0.f, 0.f, 0.f, 0.f);
  int i = i0;
  for (; i + 4 <= i1; i += 4) {  // 4 gathers in flight
    int s0 = csr[i], s1 = csr[i + 1], s2 = csr[i + 2], s3 = csr[i + 3];
    float4 v0 = xp[(size_t)s0 * 64 + lane];
    float4 v1 = xp[(size_t)s1 * 64 + lane];
    float4 v2 = xp[(size_t)s2 * 64 + lane];
    float4 v3 = xp[(size_t)s3 * 64 + lane];
    a.x += (v0.x + v1.x) + (v2.x + v3.x);
    a.y += (v0.y + v1.y) + (v2.y + v3.y);
    a.z += (v0.z + v1.z) + (v2.z + v3.z);
    a.w += (v0.w + v1.w) + (v2.w + v3.w);
  }
  for (; i < i1; i++) {
    int s = csr[i];
    float4 v = xp[(size_t)s * 64 + lane];
    a.x += v.x; a.y += v.y; a.z += v.z; a.w += v.w;
  }
  // bf16 copy for the expert GEMM
  ushort4 ab;
  ab.x = f2bf(a.x); ab.y = f2bf(a.y); ab.z = f2bf(a.z); ab.w = f2bf(a.w);
  ((ushort4*)aggb)[(size_t)n * 64 + lane] = ab;

  // gate logits: per-lane partials + full-wave shuffle reduce
  float p[NX];
#pragma unroll
  for (int e = 0; e < NX; e++) p[e] = 0.f;
  const float* wr = Wg + lane * 4 * NX;
  float av[4] = {a.x, a.y, a.z, a.w};
#pragma unroll
  for (int j = 0; j < 4; j++)
#pragma unroll
    for (int e = 0; e < NX; e++) p[e] = fmaf(av[j], wr[j * NX + e], p[e]);
#pragma unroll
  for (int off = 32; off > 0; off >>= 1)
#pragma unroll
    for (int e = 0; e < NX; e++) p[e] += __shfl_xor(p[e], off, 64);

  float lg[NX];
#pragma unroll
  for (int e = 0; e < NX; e++) lg[e] = fmaxf(p[e] + bg[e], 0.f);

  // top-3, lowest-index tie-break (matches stable lax.top_k)
  int ti0 = 0, ti1 = 0, ti2 = 0;
  float tv0 = -1.f, tv1 = -1.f, tv2 = -1.f;
#pragma unroll
  for (int e = 0; e < NX; e++) if (lg[e] > tv0) { tv0 = lg[e]; ti0 = e; }
#pragma unroll
  for (int e = 0; e < NX; e++) if (e != ti0 && lg[e] > tv1) { tv1 = lg[e]; ti1 = e; }
#pragma unroll
  for (int e = 0; e < NX; e++) if (e != ti0 && e != ti1 && lg[e] > tv2) { tv2 = lg[e]; ti2 = e; }

  float e1 = expf(tv1 - tv0), e2 = expf(tv2 - tv0);
  float inv = 1.f / (1.f + e1 + e2);
  float g0 = inv, g1 = e1 * inv, g2 = e2 * inv;

  if (lane == 0) {
    float go[NX];
#pragma unroll
    for (int e = 0; e < NX; e++)
      go[e] = (e == ti0) ? g0 : ((e == ti1) ? g1 : ((e == ti2) ? g2 : 0.f));
    float4* gp = (float4*)(gates + (size_t)n * NX);
    gp[0] = make_float4(go[0], go[1], go[2], go[3]);
    gp[1] = make_float4(go[4], go[5], go[6], go[7]);
    atomicAdd(&s_imp[ti0], g0); atomicAdd(&s_imp[ti1], g1); atomicAdd(&s_imp[ti2], g2);
    atomicAdd(&s_load[ti0], 1); atomicAdd(&s_load[ti1], 1); atomicAdd(&s_load[ti2], 1);
  }
  __syncthreads();
  if (t < NX) { atomicAdd(&imp[t], s_imp[t]); atomicAdd(&loadc[t], s_load[t]); }
}

// ---------------- aux loss ----------------
__global__ void k_loss(const float* __restrict__ imp, const int* __restrict__ loadc,
                       float* __restrict__ out) {
  if (threadIdx.x == 0 && blockIdx.x == 0) {
    double mi = 0, ml = 0;
    for (int e = 0; e < NX; e++) { mi += imp[e]; ml += (double)loadc[e]; }
    mi *= 0.125; ml *= 0.125;
    double vi = 0, vl = 0;
    for (int e = 0; e < NX; e++) {
      double di = imp[e] - mi, dl = (double)loadc[e] - ml;
      vi += di * di; vl += dl * dl;
    }
    vi /= 7.0; vl /= 7.0;  // ddof=1
    double cv = vi / (mi * mi + 1e-10) + vl / (ml * ml + 1e-10);
    out[0] = (float)(0.01 * cv);
  }
}

// ---------------- experts: 128x128 tile, LDS-staged B, dbuf, swizzled ----------------
// Chunk = (expert e, K-half h): B slice [BN cols][128 K] bf16 = 32 KB.
// LDS layout swizzled: byte (c*256 + u*16) holds global (c, d=(u^(c&7))*8)
// -> ds_read 2-way max bank aliasing (free), global_load_lds dest stays linear.
__global__ __launch_bounds__(256, 2) void k_y(
    const unsigned short* __restrict__ aggb, const unsigned short* __restrict__ Wt,
    const float* __restrict__ gates, const float* __restrict__ be,
    float* __restrict__ y) {
  __shared__ __align__(16) unsigned short ldsB[2][BN * 128];  // 2 x 32 KB
  __shared__ float ldsg[BM][12];  // gates, stride 12 (16B-aligned rows, conflict-free)
  __shared__ float ldsb[NX][BN];  // bias slice
  int t = threadIdx.x;
  int rb = blockIdx.x >> 1, cb = blockIdx.x & 1;
  int r0 = rb * BM, c0 = cb * BN;
  int wv = t >> 6, l = t & 63, l15 = l & 15, lgp = l >> 4;

  auto stageB = [&](int e, int h, int buf) {
#pragma unroll
    for (int i = 0; i < 8; i++) {
      int c = (i * 4 + wv) * 4 + lgp;           // col within slice
      int d = ((l & 15) ^ (c & 7)) * 8;         // pre-swizzled source k-offset
      const unsigned short* gp = Wt + (((e << 8) + c0 + c) << 8) + (h << 7) + d;
      __builtin_amdgcn_global_load_lds((const AS1 unsigned int*)gp,
                                       (AS3 unsigned int*)&ldsB[buf][(i * 4 + wv) * 512],
                                       16, 0, 0);
    }
  };

  // stage gates (row-major, padded) and bias slice
  {
    int r = t >> 1, hf = t & 1;
    int gr = r0 + r;
    float4 gv = make_float4(0.f, 0.f, 0.f, 0.f);
    if (gr < NN) gv = ((const float4*)gates)[(size_t)gr * 2 + hf];
    ldsg[r][hf * 4 + 0] = gv.x; ldsg[r][hf * 4 + 1] = gv.y;
    ldsg[r][hf * 4 + 2] = gv.z; ldsg[r][hf * 4 + 3] = gv.w;
  }
  {
    int e = t >> 5, c = (t & 31) * 4;
    *(float4*)&ldsb[e][c] = *(const float4*)(be + (e << 8) + c0 + c);
  }

  // A fragments in registers for the whole block lifetime
  s8v afr[2][8];
#pragma unroll
  for (int rf = 0; rf < 2; rf++) {
    int row = r0 + wv * 32 + rf * 16 + l15;
    if (row >= NN) row = NN - 1;  // clamp; gate==0 kills contribution
    const unsigned short* ap = aggb + ((size_t)row << 8) + lgp * 8;
#pragma unroll
    for (int ks = 0; ks < 8; ks++) afr[rf][ks] = *(const s8v*)(ap + ks * 32);
  }

  f4v yac[2][8];
#pragma unroll
  for (int rf = 0; rf < 2; rf++)
#pragma unroll
    for (int cf = 0; cf < 8; cf++) yac[rf][cf] = (f4v)0.0f;

  stageB(0, 0, 0);
  __syncthreads();

  for (int e = 0; e < NX; e++) {
    f4v ac[2][8];
#pragma unroll
    for (int rf = 0; rf < 2; rf++)
#pragma unroll
      for (int cf = 0; cf < 8; cf++) ac[rf][cf] = (f4v)0.0f;

#pragma unroll
    for (int h = 0; h < 2; h++) {
      if (h == 0) stageB(e, 1, 1);          // prefetch this expert's 2nd half
      else if (e < 7) stageB(e + 1, 0, 0);  // prefetch next expert's 1st half
#pragma unroll
      for (int cf = 0; cf < 8; cf++) {
        int c = cf * 16 + l15;
#pragma unroll
        for (int ksl = 0; ksl < 4; ksl++) {
          int u = (ksl * 4 + lgp) ^ (c & 7);  // swizzled 16B-unit index
          s8v b = *(const s8v*)&ldsB[h][c * 128 + u * 8];
          ac[0][cf] = __builtin_amdgcn_mfma_f32_16x16x32_bf16(afr[0][h * 4 + ksl], b, ac[0][cf], 0, 0, 0);
          ac[1][cf] = __builtin_amdgcn_mfma_f32_16x16x32_bf16(afr[1][h * 4 + ksl], b, ac[1][cf], 0, 0, 0);
        }
      }
      __syncthreads();
    }
    // fold expert e into yac with gate + bias
#pragma unroll
    for (int rf = 0; rf < 2; rf++)
#pragma unroll
      for (int r = 0; r < 4; r++) {
        float g = ldsg[wv * 32 + rf * 16 + lgp * 4 + r][e];
#pragma unroll
        for (int cf = 0; cf < 8; cf++)
          yac[rf][cf][r] += g * (ac[rf][cf][r] + ldsb[e][cf * 16 + l15]);
      }
  }

#pragma unroll
  for (int rf = 0; rf < 2; rf++)
#pragma unroll
    for (int r = 0; r < 4; r++) {
      int row = r0 + wv * 32 + rf * 16 + lgp * 4 + r;
      if (row < NN) {
#pragma unroll
        for (int cf = 0; cf < 8; cf++)
          y[(size_t)row * DD + c0 + cf * 16 + l15] = yac[rf][cf][r];
      }
    }
}

extern "C" void kernel_launch(void* const* d_in, const int* in_sizes, int n_in,
                              void* d_out, int out_size, void* d_ws, size_t ws_size,
                              hipStream_t stream) {
  const float* x  = (const float*)d_in[0];
  const int*   ei = (const int*)d_in[1];
  const float* Wg = (const float*)d_in[2];
  const float* bg = (const float*)d_in[3];
  const float* We = (const float*)d_in[4];
  const float* be = (const float*)d_in[5];
  float* y = (float*)d_out;  // [NN*DD] then loss scalar at [NN*DD]

  char* w = (char*)d_ws;
  auto alloc = [&](size_t bytes) {
    char* p = w;
    w += (bytes + 255) & ~(size_t)255;
    return p;
  };
  unsigned short* aggb   = (unsigned short*)alloc((size_t)NN * DD * 2);
  unsigned short* Wt     = (unsigned short*)alloc((size_t)NX * DD * DD * 2);
  float*          gates  = (float*)alloc((size_t)NN * NX * 4);
  int*            rowptr = (int*)alloc((size_t)(NN + 1) * 4);
  int*            cursor = (int*)alloc((size_t)NN * 4);
  int*            csr    = (int*)alloc((size_t)NE * 4);
  int*            deg    = (int*)alloc((size_t)NN * 4 + 64);  // deg | imp | loadc
  int*            bsum   = (int*)alloc(64 * 4);
  int*            boff   = (int*)alloc(64 * 4);
  float*          imp    = (float*)(deg + NN);
  int*            loadc  = deg + NN + 8;

  hipMemsetAsync(deg, 0, (size_t)NN * 4 + 64, stream);
  k_deg<<<(NE + 255) / 256, 256, 0, stream>>>(ei, deg);
  k_scan1<<<49, 1024, 0, stream>>>(deg, rowptr, bsum);
  k_scan2<<<1, 64, 0, stream>>>(bsum, boff, rowptr);
  k_scan3<<<49, 1024, 0, stream>>>(rowptr, boff, cursor);
  k_scatter<<<(NE + 255) / 256, 256, 0, stream>>>(ei, cursor, csr);
  k_wt<<<(NX * DD * DD) / 256, 256, 0, stream>>>(We, Wt);
  k_agggate<<<NN / 4, 256, 0, stream>>>(x, rowptr, csr, Wg, bg, aggb, gates, imp, loadc);
  k_loss<<<1, 64, 0, stream>>>(imp, loadc, y + (size_t)NN * DD);
  k_y<<<391 * 2, 256, 0, stream>>>(aggb, Wt, gates, be, y);
}